// Round 1
// baseline (1140.220 us; speedup 1.0000x reference)
//
#include <hip/hip_runtime.h>
#include <math.h>

#define B_   2
#define N_   10000
#define E_   160000
#define HID_ 128
#define ED_  32
#define NH_  8
#define HD_  16

// ---------------- CSR build ----------------

__global__ void zero_kernel(int* __restrict__ deg, int* __restrict__ cursor, int n) {
    int i = blockIdx.x * 256 + threadIdx.x;
    if (i < n) { deg[i] = 0; cursor[i] = 0; }
}

__global__ void hist_kernel(const int* __restrict__ ei, int* __restrict__ deg, int E) {
    int e = blockIdx.x * 256 + threadIdx.x;
    if (e < E) atomicAdd(&deg[ei[2 * e + 1]], 1);
}

__global__ __launch_bounds__(256) void scan_kernel(const int* __restrict__ deg,
                                                   int* __restrict__ off, int N) {
    __shared__ int sums[256];
    int t = threadIdx.x;
    int chunk = (N + 255) / 256;
    int s0 = t * chunk, s1 = min(N, s0 + chunk);
    int s = 0;
    for (int i = s0; i < s1; ++i) s += deg[i];
    sums[t] = s;
    __syncthreads();
    if (t == 0) {
        int run = 0;
        for (int i = 0; i < 256; ++i) { int v = sums[i]; sums[i] = run; run += v; }
        off[N] = run;
    }
    __syncthreads();
    int run = sums[t];
    for (int i = s0; i < s1; ++i) { off[i] = run; run += deg[i]; }
}

__global__ void fill_kernel(const int* __restrict__ ei, const int* __restrict__ off,
                            int* __restrict__ cursor, int* __restrict__ csr, int E) {
    int e = blockIdx.x * 256 + threadIdx.x;
    if (e < E) {
        int d = ei[2 * e + 1];
        int p = atomicAdd(&cursor[d], 1);
        csr[off[d] + p] = e;
    }
}

// ---------------- node QKV projections ----------------
// rows = B*N flattened; out[r][j] = bias[j] + sum_k h[r][k] * W[j][k]

__global__ __launch_bounds__(512) void qkv_kernel(
    const float* __restrict__ h,
    const float* __restrict__ Wq, const float* __restrict__ bq,
    const float* __restrict__ Wk, const float* __restrict__ bk,
    const float* __restrict__ Wv, const float* __restrict__ bv,
    float* __restrict__ Qn, float* __restrict__ Kn, float* __restrict__ Vn, int rows)
{
    __shared__ __align__(16) float hs[4][HID_];
    int j = threadIdx.x & 127;
    int rg = threadIdx.x >> 7;
    int row0 = blockIdx.x * 4;
    int r = row0 + rg;
    hs[rg][j] = (r < rows) ? h[(long)r * HID_ + j] : 0.f;
    __syncthreads();
    if (r >= rows) return;

    const float4* wq4 = (const float4*)(Wq + (long)j * HID_);
    const float4* wk4 = (const float4*)(Wk + (long)j * HID_);
    const float4* wv4 = (const float4*)(Wv + (long)j * HID_);
    const float4* h4  = (const float4*)hs[rg];

    float aq = bq[j], ak = bk[j], av = bv[j];
    #pragma unroll 8
    for (int k4 = 0; k4 < 32; ++k4) {
        float4 hv = h4[k4];
        float4 a = wq4[k4]; aq += a.x * hv.x + a.y * hv.y + a.z * hv.z + a.w * hv.w;
        float4 b = wk4[k4]; ak += b.x * hv.x + b.y * hv.y + b.z * hv.z + b.w * hv.w;
        float4 c = wv4[k4]; av += c.x * hv.x + c.y * hv.y + c.z * hv.z + c.w * hv.w;
    }
    long o = (long)r * HID_ + j;
    Qn[o] = aq; Kn[o] = ak; Vn[o] = av;
}

// ---------------- fused per-(b,node): edge loop + softmax-agg + update + LN ----------------

__global__ __launch_bounds__(128) void node_kernel(
    const float* __restrict__ h, const float* __restrict__ edge_attr,
    const int* __restrict__ ei,
    const float* __restrict__ Qn, const float* __restrict__ Kn, const float* __restrict__ Vn,
    const float* __restrict__ We, const float* __restrict__ be,
    const float* __restrict__ attn_vec,
    const float* __restrict__ Ws, const float* __restrict__ bs,
    const float* __restrict__ Wa, const float* __restrict__ ba,
    const float* __restrict__ ln_g, const float* __restrict__ ln_b,
    const int* __restrict__ off, const int* __restrict__ csr,
    float* __restrict__ out)
{
    int n = blockIdx.x;
    int b = blockIdx.y;
    int j = threadIdx.x;

    __shared__ __align__(16) float aggL[HID_];
    __shared__ __align__(16) float hL[HID_];
    __shared__ float red[4];

    // We row j in registers (8 x float4 = 32 floats)
    float4 we[8];
    const float4* We4 = (const float4*)(We + (long)j * ED_);
    #pragma unroll
    for (int c = 0; c < 8; ++c) we[c] = We4[c];

    float bej = be[j];
    float avj = attn_vec[j];
    long nb = (long)b * N_ + n;
    float qj = Qn[nb * HID_ + j];
    float hj = h[nb * HID_ + j];

    int o0 = off[n], o1 = off[n + 1];
    float den = 0.f, acc = 0.f;

    for (int i = o0; i < o1; ++i) {
        int e = csr[i];
        int src = ei[2 * e];
        long sb = (long)b * N_ + src;
        float kj = Kn[sb * HID_ + j];
        float vj = Vn[sb * HID_ + j];

        const float4* ea4 = (const float4*)(edge_attr + ((long)b * E_ + e) * ED_);
        float ej = bej;
        #pragma unroll
        for (int c = 0; c < 8; ++c) {
            float4 ea = ea4[c];
            ej += we[c].x * ea.x + we[c].y * ea.y + we[c].z * ea.z + we[c].w * ea.w;
        }

        float t = tanhf(qj + kj + ej);
        float p = t * avj;
        p += __shfl_xor(p, 1);
        p += __shfl_xor(p, 2);
        p += __shfl_xor(p, 4);
        p += __shfl_xor(p, 8);           // sum over 16-lane head group
        float ex = expf(p * 0.25f);      // / sqrt(HD=16); no max-sub needed (|logit|<~0.1)
        den += ex;
        acc += ex * (vj + ej);
    }

    float aggj = (den > 0.f) ? acc / den : 0.f;
    aggL[j] = aggj;
    hL[j] = hj;
    __syncthreads();

    // update[j] = bs+ba + h.Ws[j,:] + agg.Wa[j,:]
    float upd = bs[j] + ba[j];
    const float4* ws4 = (const float4*)(Ws + (long)j * HID_);
    const float4* wa4 = (const float4*)(Wa + (long)j * HID_);
    const float4* hL4 = (const float4*)hL;
    const float4* aL4 = (const float4*)aggL;
    #pragma unroll 8
    for (int k4 = 0; k4 < 32; ++k4) {
        float4 hv = hL4[k4], gv = aL4[k4];
        float4 a = ws4[k4]; upd += a.x * hv.x + a.y * hv.y + a.z * hv.z + a.w * hv.w;
        float4 c = wa4[k4]; upd += c.x * gv.x + c.y * gv.y + c.z * gv.z + c.w * gv.w;
    }

    float g = 0.5f * upd * (1.f + erff(upd * 0.70710678118654752f)); // exact gelu
    float x = hj + g;

    // LayerNorm over the 128 threads (2 waves)
    float s = x, s2 = x * x;
    #pragma unroll
    for (int m = 1; m < 64; m <<= 1) { s += __shfl_xor(s, m); s2 += __shfl_xor(s2, m); }
    int wv = j >> 6;
    if ((j & 63) == 0) { red[wv] = s; red[2 + wv] = s2; }
    __syncthreads();
    float S = red[0] + red[1], S2 = red[2] + red[3];
    float mu = S * (1.f / 128.f);
    float var = S2 * (1.f / 128.f) - mu * mu;
    float o = (x - mu) * rsqrtf(var + 1e-5f) * ln_g[j] + ln_b[j];
    out[nb * HID_ + j] = o;
}

// ---------------- launch ----------------

extern "C" void kernel_launch(void* const* d_in, const int* in_sizes, int n_in,
                              void* d_out, int out_size, void* d_ws, size_t ws_size,
                              hipStream_t stream) {
    const float* h         = (const float*)d_in[0];
    const float* edge_attr = (const float*)d_in[1];
    const int*   ei        = (const int*)  d_in[2];
    const float* Wq = (const float*)d_in[3];
    const float* bq = (const float*)d_in[4];
    const float* Wk = (const float*)d_in[5];
    const float* bk = (const float*)d_in[6];
    const float* Wv = (const float*)d_in[7];
    const float* bv = (const float*)d_in[8];
    const float* We = (const float*)d_in[9];
    const float* be = (const float*)d_in[10];
    const float* attn_vec = (const float*)d_in[11];
    const float* Ws = (const float*)d_in[12];
    const float* bs = (const float*)d_in[13];
    const float* Wa = (const float*)d_in[14];
    const float* ba = (const float*)d_in[15];
    const float* ln_g = (const float*)d_in[16];
    const float* ln_b = (const float*)d_in[17];
    float* out = (float*)d_out;

    // workspace carve-up (256B aligned)
    size_t p = 0;
    auto alloc = [&](size_t bytes) { size_t r = p; p += (bytes + 255) & ~(size_t)255; return r; };
    char* ws = (char*)d_ws;
    float* Qn  = (float*)(ws + alloc((size_t)B_ * N_ * HID_ * 4));
    float* Kn  = (float*)(ws + alloc((size_t)B_ * N_ * HID_ * 4));
    float* Vn  = (float*)(ws + alloc((size_t)B_ * N_ * HID_ * 4));
    int* deg    = (int*)(ws + alloc((size_t)N_ * 4));
    int* cursor = (int*)(ws + alloc((size_t)N_ * 4));
    int* off    = (int*)(ws + alloc((size_t)(N_ + 1) * 4));
    int* csr    = (int*)(ws + alloc((size_t)E_ * 4));
    (void)ws_size;

    // CSR build (by dst)
    zero_kernel<<<(N_ + 255) / 256, 256, 0, stream>>>(deg, cursor, N_);
    hist_kernel<<<(E_ + 255) / 256, 256, 0, stream>>>(ei, deg, E_);
    scan_kernel<<<1, 256, 0, stream>>>(deg, off, N_);
    fill_kernel<<<(E_ + 255) / 256, 256, 0, stream>>>(ei, off, cursor, csr, E_);

    // node-level QKV projections
    int rows = B_ * N_;
    qkv_kernel<<<(rows + 3) / 4, 512, 0, stream>>>(h, Wq, bq, Wk, bk, Wv, bv, Qn, Kn, Vn, rows);

    // fused edge traversal + aggregation + node update + layernorm
    dim3 grid(N_, B_);
    node_kernel<<<grid, 128, 0, stream>>>(h, edge_attr, ei, Qn, Kn, Vn,
                                          We, be, attn_vec, Ws, bs, Wa, ba,
                                          ln_g, ln_b, off, csr, out);
}

// Round 2
// 512.877 us; speedup vs baseline: 2.2232x; 2.2232x over previous
//
#include <hip/hip_runtime.h>
#include <math.h>

#define B_   2
#define N_   10000
#define E_   160000
#define HID_ 128
#define ED_  32
#define NH_  8
#define HD_  16
#define ROWS_ (B_ * N_)   // 20000

// ---------------- CSR build ----------------

__global__ void zero_kernel(int* __restrict__ deg, int* __restrict__ cursor, int n) {
    int i = blockIdx.x * 256 + threadIdx.x;
    if (i < n) { deg[i] = 0; cursor[i] = 0; }
}

__global__ void hist_kernel(const int* __restrict__ ei, int* __restrict__ deg, int E) {
    int e = blockIdx.x * 256 + threadIdx.x;
    if (e < E) atomicAdd(&deg[ei[2 * e + 1]], 1);
}

__global__ __launch_bounds__(256) void scan_kernel(const int* __restrict__ deg,
                                                   int* __restrict__ off, int N) {
    __shared__ int sums[256];
    int t = threadIdx.x;
    int chunk = (N + 255) / 256;
    int s0 = t * chunk, s1 = min(N, s0 + chunk);
    int s = 0;
    for (int i = s0; i < s1; ++i) s += deg[i];
    sums[t] = s;
    __syncthreads();
    if (t == 0) {
        int run = 0;
        for (int i = 0; i < 256; ++i) { int v = sums[i]; sums[i] = run; run += v; }
        off[N] = run;
    }
    __syncthreads();
    int run = sums[t];
    for (int i = s0; i < s1; ++i) { off[i] = run; run += deg[i]; }
}

__global__ void fill_kernel(const int* __restrict__ ei, const int* __restrict__ off,
                            int* __restrict__ cursor, int* __restrict__ csr, int E) {
    int e = blockIdx.x * 256 + threadIdx.x;
    if (e < E) {
        int d = ei[2 * e + 1];
        int p = atomicAdd(&cursor[d], 1);
        csr[off[d] + p] = e;
    }
}

// ---------------- node QKV projections: tiled LDS GEMM ----------------
// QKV[row][J], J in [0,384): 0..127 = Q, 128..255 = K, 256..383 = V
// 20000 rows, tile = 32 rows x 48 cols, 8 col-chunks, 2x3 register blocking.

#define R_T 32
#define JC_ 48
#define NCHUNK_ 8
#define LDH_ 132   // padded stride: 132 mod 32 = 4 -> 2-way bank alias only (free)

__global__ __launch_bounds__(256) void qkv_kernel(
    const float* __restrict__ h,
    const float* __restrict__ Wq, const float* __restrict__ bq,
    const float* __restrict__ Wk, const float* __restrict__ bk,
    const float* __restrict__ Wv, const float* __restrict__ bv,
    float* __restrict__ QKV)
{
    __shared__ __align__(16) float hs[R_T][LDH_];
    __shared__ __align__(16) float wsm[JC_][LDH_];
    __shared__ float bsm[384];

    int tid = threadIdx.x;
    int row0 = blockIdx.x * R_T;

    for (int f = tid; f < 384; f += 256)
        bsm[f] = (f < 128) ? bq[f] : (f < 256 ? bk[f - 128] : bv[f - 256]);

    // h tile: 32 rows x 32 float4, coalesced
    for (int f = tid; f < R_T * 32; f += 256) {
        int r = f >> 5, c4 = f & 31;
        *(float4*)(&hs[r][c4 * 4]) = *(const float4*)(h + (long)(row0 + r) * HID_ + c4 * 4);
    }

    int rg = tid & 15;   // row group: rows rg, rg+16
    int cg = tid >> 4;   // col group: cols cg, cg+16, cg+32

    for (int jc = 0; jc < NCHUNK_; ++jc) {
        __syncthreads();  // h ready (iter 0) / wsm no longer in use (iter >0)
        for (int f = tid; f < JC_ * 32; f += 256) {
            int jr = f >> 5, c4 = f & 31;
            int J = jc * JC_ + jr;
            const float* Wp = (J < 128) ? (Wq + (long)J * HID_)
                            : (J < 256) ? (Wk + (long)(J - 128) * HID_)
                                        : (Wv + (long)(J - 256) * HID_);
            *(float4*)(&wsm[jr][c4 * 4]) = *(const float4*)(Wp + c4 * 4);
        }
        __syncthreads();

        float a00 = 0.f, a01 = 0.f, a02 = 0.f, a10 = 0.f, a11 = 0.f, a12 = 0.f;
        #pragma unroll 8
        for (int k4 = 0; k4 < 32; ++k4) {
            float4 h0 = *(const float4*)(&hs[rg][k4 * 4]);
            float4 h1 = *(const float4*)(&hs[rg + 16][k4 * 4]);
            float4 w0 = *(const float4*)(&wsm[cg][k4 * 4]);
            float4 w1 = *(const float4*)(&wsm[cg + 16][k4 * 4]);
            float4 w2 = *(const float4*)(&wsm[cg + 32][k4 * 4]);
            a00 += h0.x*w0.x + h0.y*w0.y + h0.z*w0.z + h0.w*w0.w;
            a01 += h0.x*w1.x + h0.y*w1.y + h0.z*w1.z + h0.w*w1.w;
            a02 += h0.x*w2.x + h0.y*w2.y + h0.z*w2.z + h0.w*w2.w;
            a10 += h1.x*w0.x + h1.y*w0.y + h1.z*w0.z + h1.w*w0.w;
            a11 += h1.x*w1.x + h1.y*w1.y + h1.z*w1.z + h1.w*w1.w;
            a12 += h1.x*w2.x + h1.y*w2.y + h1.z*w2.z + h1.w*w2.w;
        }

        int J0 = jc * JC_ + cg;
        long r0 = (long)(row0 + rg) * 384;
        long r1 = (long)(row0 + rg + 16) * 384;
        QKV[r0 + J0]      = a00 + bsm[J0];
        QKV[r0 + J0 + 16] = a01 + bsm[J0 + 16];
        QKV[r0 + J0 + 32] = a02 + bsm[J0 + 32];
        QKV[r1 + J0]      = a10 + bsm[J0];
        QKV[r1 + J0 + 16] = a11 + bsm[J0 + 16];
        QKV[r1 + J0 + 32] = a12 + bsm[J0 + 32];
    }
}

// ---------------- fused per-(b,node): edge loop + softmax-agg + update + LN ----------------

__global__ __launch_bounds__(128) void node_kernel(
    const float* __restrict__ h, const float* __restrict__ edge_attr,
    const int* __restrict__ ei,
    const float* __restrict__ QKV,
    const float* __restrict__ We, const float* __restrict__ be,
    const float* __restrict__ attn_vec,
    const float* __restrict__ Ws, const float* __restrict__ bs,
    const float* __restrict__ Wa, const float* __restrict__ ba,
    const float* __restrict__ ln_g, const float* __restrict__ ln_b,
    const int* __restrict__ off, const int* __restrict__ csr,
    float* __restrict__ out)
{
    int n = blockIdx.x;
    int b = blockIdx.y;
    int j = threadIdx.x;

    __shared__ __align__(16) float aggL[HID_];
    __shared__ __align__(16) float hL[HID_];
    __shared__ float red[4];

    float4 we[8];
    const float4* We4 = (const float4*)(We + (long)j * ED_);
    #pragma unroll
    for (int c = 0; c < 8; ++c) we[c] = We4[c];

    float bej = be[j];
    float avj = attn_vec[j];
    long nb = (long)b * N_ + n;
    float qj = QKV[nb * 384 + j];
    float hj = h[nb * HID_ + j];

    int o0 = off[n], o1 = off[n + 1];
    float den = 0.f, acc = 0.f;

    for (int i = o0; i < o1; ++i) {
        int e = csr[i];
        int src = ei[2 * e];
        long sb = (long)b * N_ + src;
        float kj = QKV[sb * 384 + 128 + j];
        float vj = QKV[sb * 384 + 256 + j];

        const float4* ea4 = (const float4*)(edge_attr + ((long)b * E_ + e) * ED_);
        float ej = bej;
        #pragma unroll
        for (int c = 0; c < 8; ++c) {
            float4 ea = ea4[c];
            ej += we[c].x * ea.x + we[c].y * ea.y + we[c].z * ea.z + we[c].w * ea.w;
        }

        // tanh(y) = 1 - 2/(exp(2y)+1)  (fast: v_exp + v_rcp)
        float y = qj + kj + ej;
        float z = __expf(2.f * y);
        float t = 1.f - 2.f * __builtin_amdgcn_rcpf(z + 1.f);

        float p = t * avj;
        p += __shfl_xor(p, 1);
        p += __shfl_xor(p, 2);
        p += __shfl_xor(p, 4);
        p += __shfl_xor(p, 8);           // sum over 16-lane head group
        float ex = __expf(p * 0.25f);    // /sqrt(HD=16); |logit| small, no max-sub needed
        den += ex;
        acc += ex * (vj + ej);
    }

    float aggj = (o1 > o0) ? acc * __builtin_amdgcn_rcpf(den) : 0.f;
    aggL[j] = aggj;
    hL[j] = hj;
    __syncthreads();

    float upd = bs[j] + ba[j];
    const float4* ws4 = (const float4*)(Ws + (long)j * HID_);
    const float4* wa4 = (const float4*)(Wa + (long)j * HID_);
    const float4* hL4 = (const float4*)hL;
    const float4* aL4 = (const float4*)aggL;
    #pragma unroll 8
    for (int k4 = 0; k4 < 32; ++k4) {
        float4 hv = hL4[k4], gv = aL4[k4];
        float4 a = ws4[k4]; upd += a.x * hv.x + a.y * hv.y + a.z * hv.z + a.w * hv.w;
        float4 c = wa4[k4]; upd += c.x * gv.x + c.y * gv.y + c.z * gv.z + c.w * gv.w;
    }

    float g = 0.5f * upd * (1.f + erff(upd * 0.70710678118654752f)); // exact gelu
    float x = hj + g;

    float s = x, s2 = x * x;
    #pragma unroll
    for (int m = 1; m < 64; m <<= 1) { s += __shfl_xor(s, m); s2 += __shfl_xor(s2, m); }
    int wv = j >> 6;
    if ((j & 63) == 0) { red[wv] = s; red[2 + wv] = s2; }
    __syncthreads();
    float S = red[0] + red[1], S2 = red[2] + red[3];
    float mu = S * (1.f / 128.f);
    float var = S2 * (1.f / 128.f) - mu * mu;
    float o = (x - mu) * rsqrtf(var + 1e-5f) * ln_g[j] + ln_b[j];
    out[nb * HID_ + j] = o;
}

// ---------------- launch ----------------

extern "C" void kernel_launch(void* const* d_in, const int* in_sizes, int n_in,
                              void* d_out, int out_size, void* d_ws, size_t ws_size,
                              hipStream_t stream) {
    const float* h         = (const float*)d_in[0];
    const float* edge_attr = (const float*)d_in[1];
    const int*   ei        = (const int*)  d_in[2];
    const float* Wq = (const float*)d_in[3];
    const float* bq = (const float*)d_in[4];
    const float* Wk = (const float*)d_in[5];
    const float* bk = (const float*)d_in[6];
    const float* Wv = (const float*)d_in[7];
    const float* bv = (const float*)d_in[8];
    const float* We = (const float*)d_in[9];
    const float* be = (const float*)d_in[10];
    const float* attn_vec = (const float*)d_in[11];
    const float* Ws = (const float*)d_in[12];
    const float* bs = (const float*)d_in[13];
    const float* Wa = (const float*)d_in[14];
    const float* ba = (const float*)d_in[15];
    const float* ln_g = (const float*)d_in[16];
    const float* ln_b = (const float*)d_in[17];
    float* out = (float*)d_out;

    size_t p = 0;
    auto alloc = [&](size_t bytes) { size_t r = p; p += (bytes + 255) & ~(size_t)255; return r; };
    char* ws = (char*)d_ws;
    float* QKV = (float*)(ws + alloc((size_t)ROWS_ * 384 * 4));
    int* deg    = (int*)(ws + alloc((size_t)N_ * 4));
    int* cursor = (int*)(ws + alloc((size_t)N_ * 4));
    int* off    = (int*)(ws + alloc((size_t)(N_ + 1) * 4));
    int* csr    = (int*)(ws + alloc((size_t)E_ * 4));
    (void)ws_size;

    zero_kernel<<<(N_ + 255) / 256, 256, 0, stream>>>(deg, cursor, N_);
    hist_kernel<<<(E_ + 255) / 256, 256, 0, stream>>>(ei, deg, E_);
    scan_kernel<<<1, 256, 0, stream>>>(deg, off, N_);
    fill_kernel<<<(E_ + 255) / 256, 256, 0, stream>>>(ei, off, cursor, csr, E_);

    qkv_kernel<<<ROWS_ / R_T, 256, 0, stream>>>(h, Wq, bq, Wk, bk, Wv, bv, QKV);

    dim3 grid(N_, B_);
    node_kernel<<<grid, 128, 0, stream>>>(h, edge_attr, ei, QKV,
                                          We, be, attn_vec, Ws, bs, Wa, ba,
                                          ln_g, ln_b, off, csr, out);
}